// Round 3
// baseline (401.905 us; speedup 1.0000x reference)
//
#include <hip/hip_runtime.h>
#include <hip/hip_bf16.h>
#include <math.h>

#define W_    384
#define H_    384
#define HW_   (384*384)
#define C_    256
#define NOBJ  16
#define NP    128
#define N2    2048
#define NF1   (NOBJ*NP)            // 2048 key points
#define NPTS  (NOBJ*NP + NOBJ*N2)  // 34816 total sampled points
#define NG    16                   // n-groups of 128 in simdist
#define NT    8                    // 16-wide n-tiles per group
#define NBIN  96                   // 4-row bins for fused sampling

typedef __attribute__((ext_vector_type(8))) short short8;
typedef __attribute__((ext_vector_type(4))) float f32x4;

__device__ __forceinline__ unsigned short f2bf(float v) {
    unsigned int u = __float_as_uint(v);
    u += 0x7fffu + ((u >> 16) & 1u);            // RNE f32->bf16
    return (unsigned short)(u >> 16);
}

__device__ __forceinline__ int bin_of(float yimg) {
    // identical FP expression to the sampler's iy0 -> guarantees staged rows
    // cover every in-bounds tap row of every binned point
    int iy0 = (int)floorf(yimg - 0.5f);
    return min(max(iy0, 0), 383) >> 2;
}

// ---------------------------------------------------------------------------
// Binning stage (replaces the 151MB-read/75MB-write transpose + ftT re-read).
// k_binA: block g counts its own bin (no atomics, no zero-init needed).
// k_binB: exclusive scan of 96 counts -> gofs[97], cursor copy gcur.
// k_binC: scatter point ids into plist (order within bin irrelevant: each
//         point writes only its own f12 row downstream).
// ---------------------------------------------------------------------------
__global__ __launch_bounds__(256) void k_binA(const float* __restrict__ kpts,
                                              const float* __restrict__ ps2,
                                              int* __restrict__ gcnt) {
    int g = blockIdx.x;                          // 0..95
    int t = threadIdx.x;
    int c = 0;
    for (int i = t; i < NPTS; i += 256) {
        float y = (i < NF1) ? kpts[2 * i + 1] : ps2[2 * (i - NF1) + 1];
        c += (bin_of(y) == g);
    }
    #pragma unroll
    for (int off = 32; off; off >>= 1) c += __shfl_xor(c, off, 64);
    __shared__ int wred[4];
    if ((t & 63) == 0) wred[t >> 6] = c;
    __syncthreads();
    if (t == 0) gcnt[g] = wred[0] + wred[1] + wred[2] + wred[3];
}

__global__ __launch_bounds__(128) void k_binB(const int* __restrict__ gcnt,
                                              int* __restrict__ gofs,
                                              int* __restrict__ gcur) {
    __shared__ int c[NBIN], o[NBIN + 1];
    int t = threadIdx.x;
    if (t < NBIN) c[t] = gcnt[t];
    __syncthreads();
    if (t == 0) {
        int run = 0;
        for (int g = 0; g < NBIN; ++g) { o[g] = run; run += c[g]; }
        o[NBIN] = run;                           // == NPTS
    }
    __syncthreads();
    if (t < NBIN) { gofs[t] = o[t]; gcur[t] = o[t]; }
    if (t == 0) gofs[NBIN] = o[NBIN];
}

__global__ __launch_bounds__(256) void k_binC(const float* __restrict__ kpts,
                                              const float* __restrict__ ps2,
                                              int* __restrict__ gcur,
                                              int* __restrict__ plist) {
    int i = blockIdx.x * 256 + threadIdx.x;      // grid exact: 136*256 == NPTS
    float y = (i < NF1) ? kpts[2 * i + 1] : ps2[2 * (i - NF1) + 1];
    int pos = atomicAdd(&gcur[bin_of(y)], 1);
    plist[pos] = i;
}

// ---------------------------------------------------------------------------
// Fused bilinear sampler: feats [C,H,W] f32 -> f12 [NPTS, C] bf16 directly.
// Grid: 96 row-groups x 8 channel-tiles. Block stages rows 4g..4g+4 x 32
// channels as packed bf16 PAIRS in LDS (layout [r][x][cpair16] uint,
// 5*384*16*4 = 122,880 B dynamic LDS):
//   - staged writes: lanes (cp, xo) -> 64 consecutive uints = 256 B
//     conflict-free per instr;
//   - tap reads: 16 consecutive uints per point, 4 points/wave -> <=4-way.
// Per-point math (f2bf of raw feats, dy-outer/dx-inner f32 accumulation,
// final f2bf) is expression-identical to the old transpose+sample pair ->
// f12 is BIT-IDENTICAL; downstream (simdist/final) unchanged.
// HBM: 1.25 x 151 MB feats (1-row overlap per 4-row group) + 17.8 MB write,
// vs old 151+75.5(w)+71(r)+17.8 -> kernel share -~25 us.
// ---------------------------------------------------------------------------
__global__ __launch_bounds__(256) void k_sample_fused(const float* __restrict__ kpts,
                                                      const float* __restrict__ ps2,
                                                      const float* __restrict__ feats,
                                                      const int* __restrict__ gofs,
                                                      const int* __restrict__ plist,
                                                      unsigned short* __restrict__ f12) {
    extern __shared__ unsigned int su[];         // [5][384][16] uints = 122,880 B
    int bid   = blockIdx.x;
    int g     = bid >> 3;                        // 0..95
    int ct    = bid & 7;                         // 0..7
    int g4    = g * 4;
    int cbase = ct * 32;
    int t     = threadIdx.x;
    int lane  = t & 63;
    int w     = t >> 6;                          // wave 0..3
    int cp    = lane & 15;                       // channel pair 0..15
    int xo    = lane >> 4;                       // 0..3
    int xbase = w * 96;                          // wave's x-strip

    // ---- stage: rows g4..g4+4 (row 384 skipped only for g==95) ----
    #pragma unroll
    for (int r = 0; r < 5; ++r) {
        int row = g4 + r;
        if (row < 384) {
            const float* f0 = feats + (size_t)(cbase + 2 * cp) * HW_
                            + (size_t)row * 384 + xbase + xo;
            #pragma unroll
            for (int it = 0; it < 24; ++it) {
                float v0 = f0[it * 4];           // channel cbase+2cp
                float v1 = f0[it * 4 + HW_];     // channel cbase+2cp+1
                su[((r * 384) + xbase + it * 4 + xo) * 16 + cp] =
                    (unsigned)f2bf(v0) | ((unsigned)f2bf(v1) << 16);
            }
        }
    }
    __syncthreads();

    // ---- sample every point binned to this row-group ----
    int ofs = gofs[g];
    int n   = gofs[g + 1] - ofs;
    for (int base = w * 4; base < n; base += 16) {
        int i = base + xo;                       // 4 points per wave-iter
        if (i >= n) continue;                    // uniform per 16-lane group
        int pid = plist[ofs + i];
        const float* src = (pid < NF1) ? (kpts + (size_t)pid * 2)
                                       : (ps2 + (size_t)(pid - NF1) * 2);
        float x  = src[0] - 0.5f;
        float y  = src[1] - 0.5f;
        float x0 = floorf(x), y0 = floorf(y);
        int ix0 = (int)x0, iy0 = (int)y0;
        float fx = x - x0, fy = y - y0;

        float a0 = 0.f, a1 = 0.f;
        #pragma unroll
        for (int dy = 0; dy < 2; ++dy) {
            int iy = iy0 + dy;
            if (iy < 0 || iy > 383) continue;    // binning => 0 <= iy-g4 <= 4
            int rl = iy - g4;
            float wy = dy ? fy : 1.f - fy;
            #pragma unroll
            for (int dx = 0; dx < 2; ++dx) {
                int ix = ix0 + dx;
                if (ix < 0 || ix > 383) continue;
                float wgt = (dx ? fx : 1.f - fx) * wy;
                unsigned u = su[(rl * 384 + ix) * 16 + cp];
                a0 += wgt * __uint_as_float(u << 16);
                a1 += wgt * __uint_as_float(u & 0xffff0000u);
            }
        }
        *(unsigned*)(f12 + (size_t)pid * C_ + cbase + 2 * cp) =
            (unsigned)f2bf(a0) | ((unsigned)f2bf(a1) << 16);
    }
}

// Fallback sampler (tiny workspace): gathers straight from [C,H,W] f32.
__global__ __launch_bounds__(256) void k_sample_direct(const float* __restrict__ kpts,
                                                       const float* __restrict__ ps2,
                                                       const float* __restrict__ feats,
                                                       unsigned short* __restrict__ f12) {
    int point = blockIdx.x * 4 + (threadIdx.x >> 6);
    int lane  = threadIdx.x & 63;
    int cb    = lane * 4;

    const float* src = (point < NF1) ? (kpts + (size_t)point * 2)
                                     : (ps2 + (size_t)(point - NF1) * 2);
    float x  = src[0] - 0.5f, y = src[1] - 0.5f;
    float x0 = floorf(x), y0 = floorf(y);
    int ix0 = (int)x0, iy0 = (int)y0;
    float fx = x - x0, fy = y - y0;

    float acc[4] = {0.f, 0.f, 0.f, 0.f};
    #pragma unroll
    for (int dy = 0; dy < 2; ++dy) {
        #pragma unroll
        for (int dx = 0; dx < 2; ++dx) {
            int ix = ix0 + dx, iy = iy0 + dy;
            float w = (dx ? fx : 1.f - fx) * (dy ? fy : 1.f - fy);
            if (ix >= 0 && ix < W_ && iy >= 0 && iy < H_) {
                int base = iy * W_ + ix;
                #pragma unroll
                for (int u = 0; u < 4; ++u)
                    acc[u] += w * feats[(size_t)(cb + u) * HW_ + base];
            }
        }
    }
    ushort4 o;
    o.x = f2bf(acc[0]); o.y = f2bf(acc[1]); o.z = f2bf(acc[2]); o.w = f2bf(acc[3]);
    *(ushort4*)(f12 + (size_t)point * C_ + cb) = o;
}

// ---------------------------------------------------------------------------
// Kernel 3: bf16 MFMA sign-dot + masked distance stats (unchanged).
// One wave per (o, 16-p tile, 128-n group); b0/b1 ping-pong B-frags.
// MFMA layouts per m89: C/D col=lane&15, row=(lane>>4)*4+reg;
// A/B m(n)=lane&15, k=(lane>>4)*8+j. Partials layout [o][p][g].
// ---------------------------------------------------------------------------
__device__ __forceinline__ void bload(const short* bbase, int t, short8* dst) {
    const short8* bp = (const short8*)(bbase + (size_t)t * 16 * C_);
    #pragma unroll
    for (int kb = 0; kb < 8; ++kb) dst[kb] = bp[kb * 4];   // +32 bf16 per block
}

__global__ __launch_bounds__(256) void k_simdist(const unsigned short* __restrict__ f12,
                                                 const float* __restrict__ ps1,
                                                 const float* __restrict__ ps2,
                                                 float* __restrict__ pmin,
                                                 float* __restrict__ psum,
                                                 float* __restrict__ pcnt) {
    int wid  = blockIdx.x * 4 + (threadIdx.x >> 6);   // 0..2047
    int lane = threadIdx.x & 63;
    int ng = wid & 15;
    int pt = (wid >> 4) & 7;
    int o  = wid >> 7;
    int quad = lane >> 4, col = lane & 15;

    const short* f12s = (const short*)f12;
    const short8* aptr =
        (const short8*)(f12s + ((size_t)(o * NP + pt * 16 + col) * C_ + quad * 8));
    short8 a[8];
    #pragma unroll
    for (int kb = 0; kb < 8; ++kb) a[kb] = aptr[kb * 4];

    const short* bbase = f12s + ((size_t)(NF1 + o * N2 + ng * 128 + col) * C_ + quad * 8);

    const float2* ps1v = (const float2*)ps1;
    const float2* ps2v = (const float2*)ps2;
    float pxr[4], pyr[4];
    #pragma unroll
    for (int r = 0; r < 4; ++r) {
        float2 pc = ps1v[o * NP + pt * 16 + quad * 4 + r];
        pxr[r] = pc.x; pyr[r] = pc.y;
    }

    float mn[4] = {INFINITY, INFINITY, INFINITY, INFINITY};
    float sm[4] = {0.f, 0.f, 0.f, 0.f};
    float ct[4] = {0.f, 0.f, 0.f, 0.f};

    auto ctile = [&](int t, short8 (&b)[8]) {
        f32x4 acc = {0.f, 0.f, 0.f, 0.f};
        #pragma unroll
        for (int kb = 0; kb < 8; ++kb)
            acc = __builtin_amdgcn_mfma_f32_16x16x32_bf16(a[kb], b[kb], acc, 0, 0, 0);
        float2 nc = ps2v[o * N2 + ng * 128 + t * 16 + col];  // this lane's n-column
        #pragma unroll
        for (int r = 0; r < 4; ++r) {
            if (acc[r] >= 0.f) {                  // sims >= 0  <=>  dot >= 0
                float dx = pxr[r] - nc.x, dy = pyr[r] - nc.y;
                float d  = sqrtf(dx * dx + dy * dy);
                mn[r] = fminf(mn[r], d); sm[r] += d; ct[r] += 1.f;
            }
        }
    };

    short8 b0[8], b1[8];
    bload(bbase, 0, b0);
    for (int t = 0; t < NT; t += 2) {             // NT even: clean ping-pong
        bload(bbase, t + 1, b1);
        ctile(t, b0);
        if (t + 2 < NT) bload(bbase, t + 2, b0);
        ctile(t + 1, b1);
    }

    #pragma unroll
    for (int r = 0; r < 4; ++r) {
        #pragma unroll
        for (int off = 1; off < 16; off <<= 1) {
            mn[r] = fminf(mn[r], __shfl_xor(mn[r], off, 16));
            sm[r] += __shfl_xor(sm[r], off, 16);
            ct[r] += __shfl_xor(ct[r], off, 16);
        }
    }
    if (col == 0) {
        #pragma unroll
        for (int r = 0; r < 4; ++r) {
            int p   = pt * 16 + quad * 4 + r;
            int idx = (o * NP + p) * NG + ng;     // [o][p][g]
            pmin[idx] = mn[r]; psum[idx] = sm[r]; pcnt[idx] = ct[r];
        }
    }
}

// ---------------------------------------------------------------------------
// Kernel 4a/4b: combine group partials -> scalar loss across 16 CUs
// (bit-identical replication of the original single-block reduction tree).
// ---------------------------------------------------------------------------
__global__ __launch_bounds__(64) void k_final1(const float* __restrict__ pmin,
                                               const float* __restrict__ psum,
                                               const float* __restrict__ pcnt,
                                               float* __restrict__ wpart) {
    int b    = blockIdx.x;                       // 0..15
    int lane = threadIdx.x;                      // 0..63
    float tot = 0.f;
    #pragma unroll
    for (int rep = 0; rep < 2; ++rep) {
        int pair = b * 64 + lane + rep * 1024;
        int base = pair * NG;
        const float4* pm = (const float4*)(pmin + base);
        const float4* ps = (const float4*)(psum + base);
        const float4* pc = (const float4*)(pcnt + base);
        float mn = INFINITY, sm = 0.f, ct = 0.f;
        #pragma unroll
        for (int g4 = 0; g4 < 4; ++g4) {
            float4 a = pm[g4], bb = ps[g4], c = pc[g4];
            mn = fminf(mn, fminf(fminf(a.x, a.y), fminf(a.z, a.w)));
            sm += bb.x + bb.y + bb.z + bb.w;
            ct += c.x + c.y + c.z + c.w;
        }
        if (ct > 0.f) tot += 0.5f * (mn + sm / ct);
    }
    #pragma unroll
    for (int off = 32; off; off >>= 1) tot += __shfl_xor(tot, off, 64);
    if (lane == 0) wpart[b] = tot;
}

__global__ __launch_bounds__(64) void k_final2(const float* __restrict__ wpart,
                                               float* __restrict__ out) {
    int t = threadIdx.x;                         // one wave
    float v = (t < 16) ? wpart[t] : 0.f;
    #pragma unroll
    for (int off = 8; off; off >>= 1) v += __shfl_xor(v, off, 16);
    if (t == 0) out[0] = v * (1.0f / (NOBJ * NP));
}

// ---------------------------------------------------------------------------
extern "C" void kernel_launch(void* const* d_in, const int* in_sizes, int n_in,
                              void* d_out, int out_size, void* d_ws, size_t ws_size,
                              hipStream_t stream) {
    const float* ps1   = (const float*)d_in[0];  // [16,128,2]
    const float* ps2   = (const float*)d_in[1];  // [16,2048,2]
    const float* feats = (const float*)d_in[2];  // [1,256,384,384]
    const float* kpts  = (const float*)d_in[3];  // [2048,2]
    float* out = (float*)d_out;

    const size_t sz_f12  = (size_t)NPTS * C_ * sizeof(unsigned short);  // 17,825,792
    const size_t sz_part = (size_t)NOBJ * NP * NG * sizeof(float);      //    131,072
    const size_t o_pmin  = sz_f12;
    const size_t o_psum  = o_pmin + sz_part;
    const size_t o_pcnt  = o_psum + sz_part;
    const size_t o_wp    = o_pcnt + sz_part;                 // 256 B
    const size_t o_gcnt  = o_wp + 256;                       // 512 B
    const size_t o_gofs  = o_gcnt + 512;                     // 512 B
    const size_t o_gcur  = o_gofs + 512;                     // 512 B
    const size_t o_plist = o_gcur + 512;                     // 139,264 B
    const size_t need    = o_plist + (size_t)NPTS * sizeof(int);

    char* ws = (char*)d_ws;
    unsigned short* f12 = (unsigned short*)ws;
    float* pmin  = (float*)(ws + o_pmin);
    float* psum  = (float*)(ws + o_psum);
    float* pcnt  = (float*)(ws + o_pcnt);
    float* wpart = (float*)(ws + o_wp);

    if (ws_size >= need) {
        int* gcnt  = (int*)(ws + o_gcnt);
        int* gofs  = (int*)(ws + o_gofs);
        int* gcur  = (int*)(ws + o_gcur);
        int* plist = (int*)(ws + o_plist);

        k_binA<<<NBIN, 256, 0, stream>>>(kpts, ps2, gcnt);
        k_binB<<<1, 128, 0, stream>>>(gcnt, gofs, gcur);
        k_binC<<<NPTS / 256, 256, 0, stream>>>(kpts, ps2, gcur, plist);
        k_sample_fused<<<NBIN * 8, 256, 5 * 384 * 16 * sizeof(unsigned), stream>>>(
            kpts, ps2, feats, gofs, plist, f12);
        k_simdist<<<NOBJ * 8 * NG / 4, 256, 0, stream>>>(f12, ps1, ps2, pmin, psum, pcnt);
        k_final1<<<16, 64, 0, stream>>>(pmin, psum, pcnt, wpart);
        k_final2<<<1, 64, 0, stream>>>(wpart, out);
    } else {
        // Fallback: direct uncoalesced gather (correct for any workspace size).
        k_sample_direct<<<NPTS / 4, 256, 0, stream>>>(kpts, ps2, feats, f12);
        k_simdist<<<NOBJ * 8 * NG / 4, 256, 0, stream>>>(f12, ps1, ps2, pmin, psum, pcnt);
        k_final1<<<16, 64, 0, stream>>>(pmin, psum, pcnt, wpart);
        k_final2<<<1, 64, 0, stream>>>(wpart, out);
    }
}

// Round 4
// 349.418 us; speedup vs baseline: 1.1502x; 1.1502x over previous
//
#include <hip/hip_runtime.h>
#include <hip/hip_bf16.h>
#include <math.h>

#define W_    384
#define H_    384
#define HW_   (384*384)
#define C_    256
#define NOBJ  16
#define NP    128
#define N2    2048
#define NF1   (NOBJ*NP)            // 2048 key points
#define NPTS  (NOBJ*NP + NOBJ*N2)  // 34816 total sampled points
#define NG    16                   // n-groups of 128 in simdist
#define NT    8                    // 16-wide n-tiles per group
#define NBIN  96                   // 4-row bins for fused sampling
#define CPB   16                   // channels per fused block
#define QPB   8                    // channel pairs per fused block
#define XPAD  388                  // padded x-stride (uints): rows 16B-aligned,
                                   // read banks (4q+ix)%32 conflict-free

typedef __attribute__((ext_vector_type(8))) short short8;
typedef __attribute__((ext_vector_type(4))) float f32x4;

__device__ __forceinline__ unsigned short f2bf(float v) {
    unsigned int u = __float_as_uint(v);
    u += 0x7fffu + ((u >> 16) & 1u);            // RNE f32->bf16
    return (unsigned short)(u >> 16);
}

__device__ __forceinline__ int bin_of(float yimg) {
    // identical FP expression to the sampler's iy0 -> staged rows cover every
    // in-bounds tap row of every binned point
    int iy0 = (int)floorf(yimg - 0.5f);
    return min(max(iy0, 0), 383) >> 2;
}

// ---------------------------------------------------------------------------
// Binning: k_binA counts per bin (one block per bin, no atomics/no zero-init);
// k_binB serial-scans 96 counts; k_binC scatters packed {pid,x,y} records
// (order within bin irrelevant: each point owns its f12 row downstream).
// ---------------------------------------------------------------------------
__global__ __launch_bounds__(256) void k_binA(const float* __restrict__ kpts,
                                              const float* __restrict__ ps2,
                                              int* __restrict__ gcnt) {
    int g = blockIdx.x;                          // 0..95
    int t = threadIdx.x;
    int c = 0;
    for (int i = t; i < NPTS; i += 256) {
        float y = (i < NF1) ? kpts[2 * i + 1] : ps2[2 * (i - NF1) + 1];
        c += (bin_of(y) == g);
    }
    #pragma unroll
    for (int off = 32; off; off >>= 1) c += __shfl_xor(c, off, 64);
    __shared__ int wred[4];
    if ((t & 63) == 0) wred[t >> 6] = c;
    __syncthreads();
    if (t == 0) gcnt[g] = wred[0] + wred[1] + wred[2] + wred[3];
}

__global__ __launch_bounds__(128) void k_binB(const int* __restrict__ gcnt,
                                              int* __restrict__ gofs,
                                              int* __restrict__ gcur) {
    __shared__ int c[NBIN], o[NBIN + 1];
    int t = threadIdx.x;
    if (t < NBIN) c[t] = gcnt[t];
    __syncthreads();
    if (t == 0) {
        int run = 0;
        for (int g = 0; g < NBIN; ++g) { o[g] = run; run += c[g]; }
        o[NBIN] = run;                           // == NPTS
    }
    __syncthreads();
    if (t < NBIN) { gofs[t] = o[t]; gcur[t] = o[t]; }
    if (t == 0) gofs[NBIN] = o[NBIN];
}

__global__ __launch_bounds__(256) void k_binC(const float* __restrict__ kpts,
                                              const float* __restrict__ ps2,
                                              int* __restrict__ gcur,
                                              int4* __restrict__ prec) {
    int i = blockIdx.x * 256 + threadIdx.x;      // grid exact: 136*256 == NPTS
    const float* src = (i < NF1) ? (kpts + (size_t)i * 2)
                                 : (ps2 + (size_t)(i - NF1) * 2);
    float px = src[0], py = src[1];
    int pos = atomicAdd(&gcur[bin_of(py)], 1);
    prec[pos] = make_int4(i, __float_as_int(px), __float_as_int(py), 0);
}

// ---------------------------------------------------------------------------
// Fused bilinear sampler v2: feats [C,H,W] f32 -> f12 [NPTS, C] bf16.
// Grid 96 row-groups x 16 channel-tiles of 16 channels. Fixes of v3:
//   * LDS 62,080 B ([5 rows][8 pairs][388 x] uint) -> 2 blocks/CU, 8 waves/CU
//     (v3: 122,880 B -> 1 block/CU, the latency killer).
//   * staging: per unit (r,q,chunk) TWO coalesced float4 loads (chan pair,
//     consecutive lanes = consecutive 16B -> 384B-contiguous runs), pack to
//     4 bf16-pair uints, ONE 16B-aligned ds_write_b128 (sequential -> 0-conflict).
//     30 float4 loads + 15 LDS writes per thread (v3: 240 scalar gathers).
//   * tap reads: word (rl*8+q)*388 + ix -> banks (4q+ix)%32, 8 distinct per
//     point, conflict-free.
// Per-point math identical to v3/old pipeline (f2bf on stage, dy-outer
// dx-inner accumulate, f2bf on store) -> f12 BIT-IDENTICAL.
// ---------------------------------------------------------------------------
__global__ __launch_bounds__(256) void k_sample_fused(const float* __restrict__ feats,
                                                      const int* __restrict__ gofs,
                                                      const int4* __restrict__ prec,
                                                      unsigned short* __restrict__ f12) {
    __shared__ unsigned su[5 * QPB * XPAD];      // 62,080 B
    int bid   = blockIdx.x;
    int g     = bid >> 4;                        // 0..95
    int ct    = bid & 15;                        // 0..15
    int g4    = g * 4;
    int cbase = ct * CPB;
    int t     = threadIdx.x;

    // ---- stage rows g4..g4+4 x 16 channels (bf16 pairs) ----
    // 3840 units = 5r x 8q x 96 chunks; 15 per thread.
    #pragma unroll
    for (int pass = 0; pass < 15; ++pass) {
        int flat  = pass * 256 + t;
        int rq    = flat / 96;                   // r*8+q, 0..39
        int chunk = flat - rq * 96;              // 0..95 (x = 4*chunk..+3)
        int r     = rq >> 3;
        int q     = rq & 7;
        int row   = g4 + r;
        if (row < 384) {                         // r==4 skipped only for g==95
            const float* p0 = feats + (size_t)(cbase + 2 * q) * HW_
                            + (size_t)row * 384 + chunk * 4;
            float4 v0 = *(const float4*)p0;        // channel cbase+2q
            float4 v1 = *(const float4*)(p0 + HW_);// channel cbase+2q+1
            uint4 pk;
            pk.x = (unsigned)f2bf(v0.x) | ((unsigned)f2bf(v1.x) << 16);
            pk.y = (unsigned)f2bf(v0.y) | ((unsigned)f2bf(v1.y) << 16);
            pk.z = (unsigned)f2bf(v0.z) | ((unsigned)f2bf(v1.z) << 16);
            pk.w = (unsigned)f2bf(v0.w) | ((unsigned)f2bf(v1.w) << 16);
            *(uint4*)&su[rq * XPAD + chunk * 4] = pk;   // 16B-aligned (388*4%16==0)
        }
    }
    __syncthreads();

    // ---- sample: 8 points per wave x 8 pair-lanes each ----
    int ofs  = gofs[g];
    int n    = gofs[g + 1] - ofs;
    int w    = t >> 6;
    int lane = t & 63;
    int pj   = lane >> 3;                        // point slot 0..7
    int q    = lane & 7;                         // channel pair
    for (int base = w * 8; base < n; base += 32) {
        int i = base + pj;
        if (i < n) {                             // uniform per 8-lane group
            int4 rec = prec[ofs + i];            // broadcast 16B
            int pid  = rec.x;
            float x  = __int_as_float(rec.y) - 0.5f;
            float y  = __int_as_float(rec.z) - 0.5f;
            float x0 = floorf(x), y0 = floorf(y);
            int ix0 = (int)x0, iy0 = (int)y0;
            float fx = x - x0, fy = y - y0;

            float a0 = 0.f, a1 = 0.f;
            #pragma unroll
            for (int dy = 0; dy < 2; ++dy) {
                int iy = iy0 + dy;
                if (iy < 0 || iy > 383) continue;  // binning => 0 <= iy-g4 <= 4
                int rl   = iy - g4;
                float wy = dy ? fy : 1.f - fy;
                #pragma unroll
                for (int dx = 0; dx < 2; ++dx) {
                    int ix = ix0 + dx;
                    if (ix < 0 || ix > 383) continue;
                    float wgt  = (dx ? fx : 1.f - fx) * wy;
                    unsigned u = su[(rl * 8 + q) * XPAD + ix];
                    a0 += wgt * __uint_as_float(u << 16);
                    a1 += wgt * __uint_as_float(u & 0xffff0000u);
                }
            }
            *(unsigned*)(f12 + (size_t)pid * C_ + cbase + 2 * q) =
                (unsigned)f2bf(a0) | ((unsigned)f2bf(a1) << 16);
        }
    }
}

// Fallback sampler (tiny workspace): gathers straight from [C,H,W] f32.
__global__ __launch_bounds__(256) void k_sample_direct(const float* __restrict__ kpts,
                                                       const float* __restrict__ ps2,
                                                       const float* __restrict__ feats,
                                                       unsigned short* __restrict__ f12) {
    int point = blockIdx.x * 4 + (threadIdx.x >> 6);
    int lane  = threadIdx.x & 63;
    int cb    = lane * 4;

    const float* src = (point < NF1) ? (kpts + (size_t)point * 2)
                                     : (ps2 + (size_t)(point - NF1) * 2);
    float x  = src[0] - 0.5f, y = src[1] - 0.5f;
    float x0 = floorf(x), y0 = floorf(y);
    int ix0 = (int)x0, iy0 = (int)y0;
    float fx = x - x0, fy = y - y0;

    float acc[4] = {0.f, 0.f, 0.f, 0.f};
    #pragma unroll
    for (int dy = 0; dy < 2; ++dy) {
        #pragma unroll
        for (int dx = 0; dx < 2; ++dx) {
            int ix = ix0 + dx, iy = iy0 + dy;
            float w = (dx ? fx : 1.f - fx) * (dy ? fy : 1.f - fy);
            if (ix >= 0 && ix < W_ && iy >= 0 && iy < H_) {
                int base = iy * W_ + ix;
                #pragma unroll
                for (int u = 0; u < 4; ++u)
                    acc[u] += w * feats[(size_t)(cb + u) * HW_ + base];
            }
        }
    }
    ushort4 o;
    o.x = f2bf(acc[0]); o.y = f2bf(acc[1]); o.z = f2bf(acc[2]); o.w = f2bf(acc[3]);
    *(ushort4*)(f12 + (size_t)point * C_ + cb) = o;
}

// ---------------------------------------------------------------------------
// Kernel 3: bf16 MFMA sign-dot + masked distance stats (unchanged).
// ---------------------------------------------------------------------------
__device__ __forceinline__ void bload(const short* bbase, int t, short8* dst) {
    const short8* bp = (const short8*)(bbase + (size_t)t * 16 * C_);
    #pragma unroll
    for (int kb = 0; kb < 8; ++kb) dst[kb] = bp[kb * 4];
}

__global__ __launch_bounds__(256) void k_simdist(const unsigned short* __restrict__ f12,
                                                 const float* __restrict__ ps1,
                                                 const float* __restrict__ ps2,
                                                 float* __restrict__ pmin,
                                                 float* __restrict__ psum,
                                                 float* __restrict__ pcnt) {
    int wid  = blockIdx.x * 4 + (threadIdx.x >> 6);   // 0..2047
    int lane = threadIdx.x & 63;
    int ng = wid & 15;
    int pt = (wid >> 4) & 7;
    int o  = wid >> 7;
    int quad = lane >> 4, col = lane & 15;

    const short* f12s = (const short*)f12;
    const short8* aptr =
        (const short8*)(f12s + ((size_t)(o * NP + pt * 16 + col) * C_ + quad * 8));
    short8 a[8];
    #pragma unroll
    for (int kb = 0; kb < 8; ++kb) a[kb] = aptr[kb * 4];

    const short* bbase = f12s + ((size_t)(NF1 + o * N2 + ng * 128 + col) * C_ + quad * 8);

    const float2* ps1v = (const float2*)ps1;
    const float2* ps2v = (const float2*)ps2;
    float pxr[4], pyr[4];
    #pragma unroll
    for (int r = 0; r < 4; ++r) {
        float2 pc = ps1v[o * NP + pt * 16 + quad * 4 + r];
        pxr[r] = pc.x; pyr[r] = pc.y;
    }

    float mn[4] = {INFINITY, INFINITY, INFINITY, INFINITY};
    float sm[4] = {0.f, 0.f, 0.f, 0.f};
    float ct[4] = {0.f, 0.f, 0.f, 0.f};

    auto ctile = [&](int t, short8 (&b)[8]) {
        f32x4 acc = {0.f, 0.f, 0.f, 0.f};
        #pragma unroll
        for (int kb = 0; kb < 8; ++kb)
            acc = __builtin_amdgcn_mfma_f32_16x16x32_bf16(a[kb], b[kb], acc, 0, 0, 0);
        float2 nc = ps2v[o * N2 + ng * 128 + t * 16 + col];
        #pragma unroll
        for (int r = 0; r < 4; ++r) {
            if (acc[r] >= 0.f) {                  // sims >= 0  <=>  dot >= 0
                float dx = pxr[r] - nc.x, dy = pyr[r] - nc.y;
                float d  = sqrtf(dx * dx + dy * dy);
                mn[r] = fminf(mn[r], d); sm[r] += d; ct[r] += 1.f;
            }
        }
    };

    short8 b0[8], b1[8];
    bload(bbase, 0, b0);
    for (int t = 0; t < NT; t += 2) {
        bload(bbase, t + 1, b1);
        ctile(t, b0);
        if (t + 2 < NT) bload(bbase, t + 2, b0);
        ctile(t + 1, b1);
    }

    #pragma unroll
    for (int r = 0; r < 4; ++r) {
        #pragma unroll
        for (int off = 1; off < 16; off <<= 1) {
            mn[r] = fminf(mn[r], __shfl_xor(mn[r], off, 16));
            sm[r] += __shfl_xor(sm[r], off, 16);
            ct[r] += __shfl_xor(ct[r], off, 16);
        }
    }
    if (col == 0) {
        #pragma unroll
        for (int r = 0; r < 4; ++r) {
            int p   = pt * 16 + quad * 4 + r;
            int idx = (o * NP + p) * NG + ng;     // [o][p][g]
            pmin[idx] = mn[r]; psum[idx] = sm[r]; pcnt[idx] = ct[r];
        }
    }
}

// ---------------------------------------------------------------------------
// Kernel 4a/4b: combine group partials -> scalar loss across 16 CUs
// (bit-identical replication of the original single-block reduction tree).
// ---------------------------------------------------------------------------
__global__ __launch_bounds__(64) void k_final1(const float* __restrict__ pmin,
                                               const float* __restrict__ psum,
                                               const float* __restrict__ pcnt,
                                               float* __restrict__ wpart) {
    int b    = blockIdx.x;                       // 0..15
    int lane = threadIdx.x;                      // 0..63
    float tot = 0.f;
    #pragma unroll
    for (int rep = 0; rep < 2; ++rep) {
        int pair = b * 64 + lane + rep * 1024;
        int base = pair * NG;
        const float4* pm = (const float4*)(pmin + base);
        const float4* ps = (const float4*)(psum + base);
        const float4* pc = (const float4*)(pcnt + base);
        float mn = INFINITY, sm = 0.f, ct = 0.f;
        #pragma unroll
        for (int g4 = 0; g4 < 4; ++g4) {
            float4 a = pm[g4], bb = ps[g4], c = pc[g4];
            mn = fminf(mn, fminf(fminf(a.x, a.y), fminf(a.z, a.w)));
            sm += bb.x + bb.y + bb.z + bb.w;
            ct += c.x + c.y + c.z + c.w;
        }
        if (ct > 0.f) tot += 0.5f * (mn + sm / ct);
    }
    #pragma unroll
    for (int off = 32; off; off >>= 1) tot += __shfl_xor(tot, off, 64);
    if (lane == 0) wpart[b] = tot;
}

__global__ __launch_bounds__(64) void k_final2(const float* __restrict__ wpart,
                                               float* __restrict__ out) {
    int t = threadIdx.x;
    float v = (t < 16) ? wpart[t] : 0.f;
    #pragma unroll
    for (int off = 8; off; off >>= 1) v += __shfl_xor(v, off, 16);
    if (t == 0) out[0] = v * (1.0f / (NOBJ * NP));
}

// ---------------------------------------------------------------------------
extern "C" void kernel_launch(void* const* d_in, const int* in_sizes, int n_in,
                              void* d_out, int out_size, void* d_ws, size_t ws_size,
                              hipStream_t stream) {
    const float* ps1   = (const float*)d_in[0];  // [16,128,2]
    const float* ps2   = (const float*)d_in[1];  // [16,2048,2]
    const float* feats = (const float*)d_in[2];  // [1,256,384,384]
    const float* kpts  = (const float*)d_in[3];  // [2048,2]
    float* out = (float*)d_out;

    const size_t sz_f12  = (size_t)NPTS * C_ * sizeof(unsigned short);  // 17,825,792
    const size_t sz_part = (size_t)NOBJ * NP * NG * sizeof(float);      //    131,072
    const size_t o_pmin  = sz_f12;
    const size_t o_psum  = o_pmin + sz_part;
    const size_t o_pcnt  = o_psum + sz_part;
    const size_t o_wp    = o_pcnt + sz_part;                 // 256 B
    const size_t o_gcnt  = o_wp + 256;                       // 512 B
    const size_t o_gofs  = o_gcnt + 512;                     // 512 B
    const size_t o_gcur  = o_gofs + 512;                     // 512 B
    const size_t o_prec  = o_gcur + 512;                     // NPTS*16 B
    const size_t need    = o_prec + (size_t)NPTS * sizeof(int4);

    char* ws = (char*)d_ws;
    unsigned short* f12 = (unsigned short*)ws;
    float* pmin  = (float*)(ws + o_pmin);
    float* psum  = (float*)(ws + o_psum);
    float* pcnt  = (float*)(ws + o_pcnt);
    float* wpart = (float*)(ws + o_wp);

    if (ws_size >= need) {
        int*  gcnt = (int*)(ws + o_gcnt);
        int*  gofs = (int*)(ws + o_gofs);
        int*  gcur = (int*)(ws + o_gcur);
        int4* prec = (int4*)(ws + o_prec);

        k_binA<<<NBIN, 256, 0, stream>>>(kpts, ps2, gcnt);
        k_binB<<<1, 128, 0, stream>>>(gcnt, gofs, gcur);
        k_binC<<<NPTS / 256, 256, 0, stream>>>(kpts, ps2, gcur, prec);
        k_sample_fused<<<NBIN * 16, 256, 0, stream>>>(feats, gofs, prec, f12);
        k_simdist<<<NOBJ * 8 * NG / 4, 256, 0, stream>>>(f12, ps1, ps2, pmin, psum, pcnt);
        k_final1<<<16, 64, 0, stream>>>(pmin, psum, pcnt, wpart);
        k_final2<<<1, 64, 0, stream>>>(wpart, out);
    } else {
        // Fallback: direct uncoalesced gather (correct for any workspace size).
        k_sample_direct<<<NPTS / 4, 256, 0, stream>>>(kpts, ps2, feats, f12);
        k_simdist<<<NOBJ * 8 * NG / 4, 256, 0, stream>>>(f12, ps1, ps2, pmin, psum, pcnt);
        k_final1<<<16, 64, 0, stream>>>(pmin, psum, pcnt, wpart);
        k_final2<<<1, 64, 0, stream>>>(wpart, out);
    }
}

// Round 5
// 337.119 us; speedup vs baseline: 1.1922x; 1.0365x over previous
//
#include <hip/hip_runtime.h>
#include <hip/hip_bf16.h>
#include <math.h>

#define W_    384
#define H_    384
#define HW_   (384*384)
#define C_    256
#define NOBJ  16
#define NP    128
#define N2    2048
#define NF1   (NOBJ*NP)            // 2048 key points
#define NPTS  (NOBJ*NP + NOBJ*N2)  // 34816 total sampled points
#define NG    16                   // n-groups of 128 in simdist
#define NT    8                    // 16-wide n-tiles per group
#define NBIN  96                   // 4-row bins for fused sampling
#define CPB   8                    // channels per fused block (v3: 16 -> 8)
#define QPB   4                    // channel pairs per fused block
#define NCT   (C_ / CPB)           // 32 channel tiles
#define XPAD  388                  // padded x-stride (uints), rows 16B-aligned

typedef __attribute__((ext_vector_type(8))) short short8;
typedef __attribute__((ext_vector_type(4))) float f32x4;

__device__ __forceinline__ unsigned short f2bf(float v) {
    unsigned int u = __float_as_uint(v);
    u += 0x7fffu + ((u >> 16) & 1u);            // RNE f32->bf16
    return (unsigned short)(u >> 16);
}

__device__ __forceinline__ int bin_of(float yimg) {
    // identical FP expression to the sampler's iy0 -> staged rows cover every
    // in-bounds tap row of every binned point
    int iy0 = (int)floorf(yimg - 0.5f);
    return min(max(iy0, 0), 383) >> 2;
}

// ---------------------------------------------------------------------------
// Binning: k_binA counts per bin (one block per bin, no atomics/no zero-init);
// k_binB serial-scans 96 counts; k_binC scatters packed {pid,x,y} records
// (order within bin irrelevant: each point owns its f12 row downstream).
// ---------------------------------------------------------------------------
__global__ __launch_bounds__(256) void k_binA(const float* __restrict__ kpts,
                                              const float* __restrict__ ps2,
                                              int* __restrict__ gcnt) {
    int g = blockIdx.x;                          // 0..95
    int t = threadIdx.x;
    int c = 0;
    for (int i = t; i < NPTS; i += 256) {
        float y = (i < NF1) ? kpts[2 * i + 1] : ps2[2 * (i - NF1) + 1];
        c += (bin_of(y) == g);
    }
    #pragma unroll
    for (int off = 32; off; off >>= 1) c += __shfl_xor(c, off, 64);
    __shared__ int wred[4];
    if ((t & 63) == 0) wred[t >> 6] = c;
    __syncthreads();
    if (t == 0) gcnt[g] = wred[0] + wred[1] + wred[2] + wred[3];
}

__global__ __launch_bounds__(128) void k_binB(const int* __restrict__ gcnt,
                                              int* __restrict__ gofs,
                                              int* __restrict__ gcur) {
    __shared__ int c[NBIN], o[NBIN + 1];
    int t = threadIdx.x;
    if (t < NBIN) c[t] = gcnt[t];
    __syncthreads();
    if (t == 0) {
        int run = 0;
        for (int g = 0; g < NBIN; ++g) { o[g] = run; run += c[g]; }
        o[NBIN] = run;                           // == NPTS
    }
    __syncthreads();
    if (t < NBIN) { gofs[t] = o[t]; gcur[t] = o[t]; }
    if (t == 0) gofs[NBIN] = o[NBIN];
}

__global__ __launch_bounds__(256) void k_binC(const float* __restrict__ kpts,
                                              const float* __restrict__ ps2,
                                              int* __restrict__ gcur,
                                              int4* __restrict__ prec) {
    int i = blockIdx.x * 256 + threadIdx.x;      // grid exact: 136*256 == NPTS
    const float* src = (i < NF1) ? (kpts + (size_t)i * 2)
                                 : (ps2 + (size_t)(i - NF1) * 2);
    float px = src[0], py = src[1];
    int pos = atomicAdd(&gcur[bin_of(py)], 1);
    prec[pos] = make_int4(i, __float_as_int(px), __float_as_int(py), 0);
}

// ---------------------------------------------------------------------------
// Fused bilinear sampler v3: feats [C,H,W] f32 -> f12 [NPTS, C] bf16.
// Grid 96 row-groups x 32 channel-tiles of 8 channels.
// v2 post-mortem: 92.8us, Occupancy 20% (LDS 62.5K -> 2 blocks/CU), VALU 14%,
// HBM 15% -> latency-bound with nothing to hide it. v3 single lever: LDS
// 31,040 B ([5 rows][4 pairs][388 x] uint) -> 5 blocks/CU -> 20 waves/CU
// (62% cap, 2.5x v2). Staging volume unchanged in total; per-point math is
// replicated 32x instead of 16x but halves per visit (latency dominates,
// not VALU). Tap reads: banks (4q+ix)%32 -> 4 distinct per point.
// Per-point math identical to v2/old pipeline (f2bf on stage, dy-outer
// dx-inner accumulate, f2bf on store) -> f12 BIT-IDENTICAL.
// ---------------------------------------------------------------------------
__global__ __launch_bounds__(256) void k_sample_fused(const float* __restrict__ feats,
                                                      const int* __restrict__ gofs,
                                                      const int4* __restrict__ prec,
                                                      unsigned short* __restrict__ f12) {
    __shared__ unsigned su[5 * QPB * XPAD];      // 31,040 B
    int bid   = blockIdx.x;
    int g     = bid >> 5;                        // 0..95
    int ct    = bid & 31;                        // 0..31
    int g4    = g * 4;
    int cbase = ct * CPB;
    int t     = threadIdx.x;

    // ---- stage rows g4..g4+4 x 8 channels (bf16 pairs) ----
    // 1920 units = 5r x 4q x 96 chunks; 8 passes of 256 (last partial).
    #pragma unroll
    for (int pass = 0; pass < 8; ++pass) {
        int flat = pass * 256 + t;
        if (flat < 5 * QPB * 96) {
            int rq    = flat / 96;               // r*4+q, 0..19
            int chunk = flat - rq * 96;          // 0..95 (x = 4*chunk..+3)
            int r     = rq >> 2;
            int q     = rq & 3;
            int row   = g4 + r;
            if (row < 384) {                     // r==4 skipped only for g==95
                const float* p0 = feats + (size_t)(cbase + 2 * q) * HW_
                                + (size_t)row * 384 + chunk * 4;
                float4 v0 = *(const float4*)p0;        // channel cbase+2q
                float4 v1 = *(const float4*)(p0 + HW_);// channel cbase+2q+1
                uint4 pk;
                pk.x = (unsigned)f2bf(v0.x) | ((unsigned)f2bf(v1.x) << 16);
                pk.y = (unsigned)f2bf(v0.y) | ((unsigned)f2bf(v1.y) << 16);
                pk.z = (unsigned)f2bf(v0.z) | ((unsigned)f2bf(v1.z) << 16);
                pk.w = (unsigned)f2bf(v0.w) | ((unsigned)f2bf(v1.w) << 16);
                *(uint4*)&su[rq * XPAD + chunk * 4] = pk;   // 16B-aligned
            }
        }
    }
    __syncthreads();

    // ---- sample: 16 points per wave x 4 pair-lanes each ----
    int ofs  = gofs[g];
    int n    = gofs[g + 1] - ofs;
    int w    = t >> 6;
    int lane = t & 63;
    int pj   = lane >> 2;                        // point slot 0..15
    int q    = lane & 3;                         // channel pair 0..3
    for (int base = w * 16; base < n; base += 64) {
        int i = base + pj;
        if (i < n) {                             // uniform per 4-lane group
            int4 rec = prec[ofs + i];            // coalesced 256B per wave
            int pid  = rec.x;
            float x  = __int_as_float(rec.y) - 0.5f;
            float y  = __int_as_float(rec.z) - 0.5f;
            float x0 = floorf(x), y0 = floorf(y);
            int ix0 = (int)x0, iy0 = (int)y0;
            float fx = x - x0, fy = y - y0;

            float a0 = 0.f, a1 = 0.f;
            #pragma unroll
            for (int dy = 0; dy < 2; ++dy) {
                int iy = iy0 + dy;
                if (iy < 0 || iy > 383) continue;  // binning => 0 <= iy-g4 <= 4
                int rl   = iy - g4;
                float wy = dy ? fy : 1.f - fy;
                #pragma unroll
                for (int dx = 0; dx < 2; ++dx) {
                    int ix = ix0 + dx;
                    if (ix < 0 || ix > 383) continue;
                    float wgt  = (dx ? fx : 1.f - fx) * wy;
                    unsigned u = su[(rl * QPB + q) * XPAD + ix];
                    a0 += wgt * __uint_as_float(u << 16);
                    a1 += wgt * __uint_as_float(u & 0xffff0000u);
                }
            }
            *(unsigned*)(f12 + (size_t)pid * C_ + cbase + 2 * q) =
                (unsigned)f2bf(a0) | ((unsigned)f2bf(a1) << 16);
        }
    }
}

// Fallback sampler (tiny workspace): gathers straight from [C,H,W] f32.
__global__ __launch_bounds__(256) void k_sample_direct(const float* __restrict__ kpts,
                                                       const float* __restrict__ ps2,
                                                       const float* __restrict__ feats,
                                                       unsigned short* __restrict__ f12) {
    int point = blockIdx.x * 4 + (threadIdx.x >> 6);
    int lane  = threadIdx.x & 63;
    int cb    = lane * 4;

    const float* src = (point < NF1) ? (kpts + (size_t)point * 2)
                                     : (ps2 + (size_t)(point - NF1) * 2);
    float x  = src[0] - 0.5f, y = src[1] - 0.5f;
    float x0 = floorf(x), y0 = floorf(y);
    int ix0 = (int)x0, iy0 = (int)y0;
    float fx = x - x0, fy = y - y0;

    float acc[4] = {0.f, 0.f, 0.f, 0.f};
    #pragma unroll
    for (int dy = 0; dy < 2; ++dy) {
        #pragma unroll
        for (int dx = 0; dx < 2; ++dx) {
            int ix = ix0 + dx, iy = iy0 + dy;
            float w = (dx ? fx : 1.f - fx) * (dy ? fy : 1.f - fy);
            if (ix >= 0 && ix < W_ && iy >= 0 && iy < H_) {
                int base = iy * W_ + ix;
                #pragma unroll
                for (int u = 0; u < 4; ++u)
                    acc[u] += w * feats[(size_t)(cb + u) * HW_ + base];
            }
        }
    }
    ushort4 o;
    o.x = f2bf(acc[0]); o.y = f2bf(acc[1]); o.z = f2bf(acc[2]); o.w = f2bf(acc[3]);
    *(ushort4*)(f12 + (size_t)point * C_ + cb) = o;
}

// ---------------------------------------------------------------------------
// Kernel 3: bf16 MFMA sign-dot + masked distance stats (unchanged).
// ---------------------------------------------------------------------------
__device__ __forceinline__ void bload(const short* bbase, int t, short8* dst) {
    const short8* bp = (const short8*)(bbase + (size_t)t * 16 * C_);
    #pragma unroll
    for (int kb = 0; kb < 8; ++kb) dst[kb] = bp[kb * 4];
}

__global__ __launch_bounds__(256) void k_simdist(const unsigned short* __restrict__ f12,
                                                 const float* __restrict__ ps1,
                                                 const float* __restrict__ ps2,
                                                 float* __restrict__ pmin,
                                                 float* __restrict__ psum,
                                                 float* __restrict__ pcnt) {
    int wid  = blockIdx.x * 4 + (threadIdx.x >> 6);   // 0..2047
    int lane = threadIdx.x & 63;
    int ng = wid & 15;
    int pt = (wid >> 4) & 7;
    int o  = wid >> 7;
    int quad = lane >> 4, col = lane & 15;

    const short* f12s = (const short*)f12;
    const short8* aptr =
        (const short8*)(f12s + ((size_t)(o * NP + pt * 16 + col) * C_ + quad * 8));
    short8 a[8];
    #pragma unroll
    for (int kb = 0; kb < 8; ++kb) a[kb] = aptr[kb * 4];

    const short* bbase = f12s + ((size_t)(NF1 + o * N2 + ng * 128 + col) * C_ + quad * 8);

    const float2* ps1v = (const float2*)ps1;
    const float2* ps2v = (const float2*)ps2;
    float pxr[4], pyr[4];
    #pragma unroll
    for (int r = 0; r < 4; ++r) {
        float2 pc = ps1v[o * NP + pt * 16 + quad * 4 + r];
        pxr[r] = pc.x; pyr[r] = pc.y;
    }

    float mn[4] = {INFINITY, INFINITY, INFINITY, INFINITY};
    float sm[4] = {0.f, 0.f, 0.f, 0.f};
    float ct[4] = {0.f, 0.f, 0.f, 0.f};

    auto ctile = [&](int t, short8 (&b)[8]) {
        f32x4 acc = {0.f, 0.f, 0.f, 0.f};
        #pragma unroll
        for (int kb = 0; kb < 8; ++kb)
            acc = __builtin_amdgcn_mfma_f32_16x16x32_bf16(a[kb], b[kb], acc, 0, 0, 0);
        float2 nc = ps2v[o * N2 + ng * 128 + t * 16 + col];
        #pragma unroll
        for (int r = 0; r < 4; ++r) {
            if (acc[r] >= 0.f) {                  // sims >= 0  <=>  dot >= 0
                float dx = pxr[r] - nc.x, dy = pyr[r] - nc.y;
                float d  = sqrtf(dx * dx + dy * dy);
                mn[r] = fminf(mn[r], d); sm[r] += d; ct[r] += 1.f;
            }
        }
    };

    short8 b0[8], b1[8];
    bload(bbase, 0, b0);
    for (int t = 0; t < NT; t += 2) {
        bload(bbase, t + 1, b1);
        ctile(t, b0);
        if (t + 2 < NT) bload(bbase, t + 2, b0);
        ctile(t + 1, b1);
    }

    #pragma unroll
    for (int r = 0; r < 4; ++r) {
        #pragma unroll
        for (int off = 1; off < 16; off <<= 1) {
            mn[r] = fminf(mn[r], __shfl_xor(mn[r], off, 16));
            sm[r] += __shfl_xor(sm[r], off, 16);
            ct[r] += __shfl_xor(ct[r], off, 16);
        }
    }
    if (col == 0) {
        #pragma unroll
        for (int r = 0; r < 4; ++r) {
            int p   = pt * 16 + quad * 4 + r;
            int idx = (o * NP + p) * NG + ng;     // [o][p][g]
            pmin[idx] = mn[r]; psum[idx] = sm[r]; pcnt[idx] = ct[r];
        }
    }
}

// ---------------------------------------------------------------------------
// Kernel 4a/4b: combine group partials -> scalar loss across 16 CUs
// (bit-identical replication of the original single-block reduction tree).
// ---------------------------------------------------------------------------
__global__ __launch_bounds__(64) void k_final1(const float* __restrict__ pmin,
                                               const float* __restrict__ psum,
                                               const float* __restrict__ pcnt,
                                               float* __restrict__ wpart) {
    int b    = blockIdx.x;                       // 0..15
    int lane = threadIdx.x;                      // 0..63
    float tot = 0.f;
    #pragma unroll
    for (int rep = 0; rep < 2; ++rep) {
        int pair = b * 64 + lane + rep * 1024;
        int base = pair * NG;
        const float4* pm = (const float4*)(pmin + base);
        const float4* ps = (const float4*)(psum + base);
        const float4* pc = (const float4*)(pcnt + base);
        float mn = INFINITY, sm = 0.f, ct = 0.f;
        #pragma unroll
        for (int g4 = 0; g4 < 4; ++g4) {
            float4 a = pm[g4], bb = ps[g4], c = pc[g4];
            mn = fminf(mn, fminf(fminf(a.x, a.y), fminf(a.z, a.w)));
            sm += bb.x + bb.y + bb.z + bb.w;
            ct += c.x + c.y + c.z + c.w;
        }
        if (ct > 0.f) tot += 0.5f * (mn + sm / ct);
    }
    #pragma unroll
    for (int off = 32; off; off >>= 1) tot += __shfl_xor(tot, off, 64);
    if (lane == 0) wpart[b] = tot;
}

__global__ __launch_bounds__(64) void k_final2(const float* __restrict__ wpart,
                                               float* __restrict__ out) {
    int t = threadIdx.x;
    float v = (t < 16) ? wpart[t] : 0.f;
    #pragma unroll
    for (int off = 8; off; off >>= 1) v += __shfl_xor(v, off, 16);
    if (t == 0) out[0] = v * (1.0f / (NOBJ * NP));
}

// ---------------------------------------------------------------------------
extern "C" void kernel_launch(void* const* d_in, const int* in_sizes, int n_in,
                              void* d_out, int out_size, void* d_ws, size_t ws_size,
                              hipStream_t stream) {
    const float* ps1   = (const float*)d_in[0];  // [16,128,2]
    const float* ps2   = (const float*)d_in[1];  // [16,2048,2]
    const float* feats = (const float*)d_in[2];  // [1,256,384,384]
    const float* kpts  = (const float*)d_in[3];  // [2048,2]
    float* out = (float*)d_out;

    const size_t sz_f12  = (size_t)NPTS * C_ * sizeof(unsigned short);  // 17,825,792
    const size_t sz_part = (size_t)NOBJ * NP * NG * sizeof(float);      //    131,072
    const size_t o_pmin  = sz_f12;
    const size_t o_psum  = o_pmin + sz_part;
    const size_t o_pcnt  = o_psum + sz_part;
    const size_t o_wp    = o_pcnt + sz_part;                 // 256 B
    const size_t o_gcnt  = o_wp + 256;                       // 512 B
    const size_t o_gofs  = o_gcnt + 512;                     // 512 B
    const size_t o_gcur  = o_gofs + 512;                     // 512 B
    const size_t o_prec  = o_gcur + 512;                     // NPTS*16 B
    const size_t need    = o_prec + (size_t)NPTS * sizeof(int4);

    char* ws = (char*)d_ws;
    unsigned short* f12 = (unsigned short*)ws;
    float* pmin  = (float*)(ws + o_pmin);
    float* psum  = (float*)(ws + o_psum);
    float* pcnt  = (float*)(ws + o_pcnt);
    float* wpart = (float*)(ws + o_wp);

    if (ws_size >= need) {
        int*  gcnt = (int*)(ws + o_gcnt);
        int*  gofs = (int*)(ws + o_gofs);
        int*  gcur = (int*)(ws + o_gcur);
        int4* prec = (int4*)(ws + o_prec);

        k_binA<<<NBIN, 256, 0, stream>>>(kpts, ps2, gcnt);
        k_binB<<<1, 128, 0, stream>>>(gcnt, gofs, gcur);
        k_binC<<<NPTS / 256, 256, 0, stream>>>(kpts, ps2, gcur, prec);
        k_sample_fused<<<NBIN * NCT, 256, 0, stream>>>(feats, gofs, prec, f12);
        k_simdist<<<NOBJ * 8 * NG / 4, 256, 0, stream>>>(f12, ps1, ps2, pmin, psum, pcnt);
        k_final1<<<16, 64, 0, stream>>>(pmin, psum, pcnt, wpart);
        k_final2<<<1, 64, 0, stream>>>(wpart, out);
    } else {
        // Fallback: direct uncoalesced gather (correct for any workspace size).
        k_sample_direct<<<NPTS / 4, 256, 0, stream>>>(kpts, ps2, feats, f12);
        k_simdist<<<NOBJ * 8 * NG / 4, 256, 0, stream>>>(f12, ps1, ps2, pmin, psum, pcnt);
        k_final1<<<16, 64, 0, stream>>>(pmin, psum, pcnt, wpart);
        k_final2<<<1, 64, 0, stream>>>(wpart, out);
    }
}

// Round 6
// 274.583 us; speedup vs baseline: 1.4637x; 1.2277x over previous
//
#include <hip/hip_runtime.h>
#include <hip/hip_bf16.h>
#include <math.h>

#define W_    384
#define H_    384
#define HW_   (384*384)
#define C_    256
#define NOBJ  16
#define NP    128
#define N2    2048
#define NF1   (NOBJ*NP)            // 2048 key points
#define NPTS  (NOBJ*NP + NOBJ*N2)  // 34816 total sampled points
#define NG    16                   // n-groups of 128 in simdist
#define NT    8                    // 16-wide n-tiles per group

typedef __attribute__((ext_vector_type(8))) short short8;
typedef __attribute__((ext_vector_type(4))) float f32x4;

__device__ __forceinline__ unsigned short f2bf(float v) {
    unsigned int u = __float_as_uint(v);
    u += 0x7fffu + ((u >> 16) & 1u);            // RNE f32->bf16
    return (unsigned short)(u >> 16);
}

// ---------------------------------------------------------------------------
// Kernel 1: transpose feats [C,H,W] f32 -> ftT [H*W, C] bf16.
// 64ch x 64pos LDS tile. Phase 1: float4 reads along p (1 KB/wave/instr).
// Phase 2: pack 8 bf16 -> uint4 store along C (1 KB/wave/instr).
// HBM-bound floor: 151 MB read + 75.5 MB write.
// ---------------------------------------------------------------------------
__global__ __launch_bounds__(256) void k_transpose(const float* __restrict__ feats,
                                                   unsigned short* __restrict__ ftT) {
    __shared__ float tile[64][65];              // +1 pad: 2-way max both phases
    int b     = blockIdx.x;
    int pbase = (b % (HW_ / 64)) * 64;
    int cbase = (b / (HW_ / 64)) * 64;
    int t     = threadIdx.x;

    int p4 = (t & 15) * 4;
    int c0 = t >> 4;                            // 0..15
    #pragma unroll
    for (int pass = 0; pass < 4; ++pass) {
        int c = c0 + pass * 16;
        float4 v = *(const float4*)(feats + (size_t)(cbase + c) * HW_ + pbase + p4);
        tile[c][p4 + 0] = v.x; tile[c][p4 + 1] = v.y;
        tile[c][p4 + 2] = v.z; tile[c][p4 + 3] = v.w;
    }
    __syncthreads();

    int c8 = (t & 7) * 8;
    int p0 = t >> 3;                            // 0..31
    #pragma unroll
    for (int pass = 0; pass < 2; ++pass) {
        int p = p0 + pass * 32;
        unsigned short u[8];
        #pragma unroll
        for (int j = 0; j < 8; ++j) u[j] = f2bf(tile[c8 + j][p]);
        uint4 pk;
        pk.x = (unsigned)u[0] | ((unsigned)u[1] << 16);
        pk.y = (unsigned)u[2] | ((unsigned)u[3] << 16);
        pk.z = (unsigned)u[4] | ((unsigned)u[5] << 16);
        pk.w = (unsigned)u[6] | ((unsigned)u[7] << 16);
        *(uint4*)(ftT + (size_t)(pbase + p) * C_ + cbase + c8) = pk;
    }
}

// ---------------------------------------------------------------------------
// Kernel 2: bilinear sample -> f12 [NPTS, C] bf16 (rows 0..2047 = f1 from
// key_points, rows 2048.. = f2 from point_set_2). Two points per wave:
// 32 lanes x 8 channels, 16 B/lane loads/stores (512 B per tap row).
// ---------------------------------------------------------------------------
__global__ __launch_bounds__(256) void k_sample(const float* __restrict__ kpts,
                                                const float* __restrict__ ps2,
                                                const unsigned short* __restrict__ ftT,
                                                unsigned short* __restrict__ f12) {
    int wave  = blockIdx.x * 4 + (threadIdx.x >> 6);
    int lane  = threadIdx.x & 63;
    int half  = lane >> 5;
    int l32   = lane & 31;
    int point = wave * 2 + half;
    int cb    = l32 * 8;

    const float* src = (point < NF1) ? (kpts + (size_t)point * 2)
                                     : (ps2 + (size_t)(point - NF1) * 2);
    // img_size == (W,H): normalization cancels; align_corners=False => -0.5
    float x  = src[0] - 0.5f;
    float y  = src[1] - 0.5f;
    float x0 = floorf(x), y0 = floorf(y);
    int ix0 = (int)x0, iy0 = (int)y0;
    float fx = x - x0, fy = y - y0;

    float a[8] = {0.f, 0.f, 0.f, 0.f, 0.f, 0.f, 0.f, 0.f};
    #pragma unroll
    for (int dy = 0; dy < 2; ++dy) {
        #pragma unroll
        for (int dx = 0; dx < 2; ++dx) {
            int ix = ix0 + dx, iy = iy0 + dy;
            float w = (dx ? fx : 1.f - fx) * (dy ? fy : 1.f - fy);
            if (ix >= 0 && ix < W_ && iy >= 0 && iy < H_) {   // half-wave uniform
                uint4 tv = *(const uint4*)(ftT + ((size_t)(iy * W_ + ix) * C_ + cb));
                a[0] += w * __uint_as_float(tv.x << 16);
                a[1] += w * __uint_as_float(tv.x & 0xffff0000u);
                a[2] += w * __uint_as_float(tv.y << 16);
                a[3] += w * __uint_as_float(tv.y & 0xffff0000u);
                a[4] += w * __uint_as_float(tv.z << 16);
                a[5] += w * __uint_as_float(tv.z & 0xffff0000u);
                a[6] += w * __uint_as_float(tv.w << 16);
                a[7] += w * __uint_as_float(tv.w & 0xffff0000u);
            }
        }
    }
    uint4 pk;
    pk.x = (unsigned)f2bf(a[0]) | ((unsigned)f2bf(a[1]) << 16);
    pk.y = (unsigned)f2bf(a[2]) | ((unsigned)f2bf(a[3]) << 16);
    pk.z = (unsigned)f2bf(a[4]) | ((unsigned)f2bf(a[5]) << 16);
    pk.w = (unsigned)f2bf(a[6]) | ((unsigned)f2bf(a[7]) << 16);
    *(uint4*)(f12 + (size_t)point * C_ + cb) = pk;
}

// Fallback sampler (no transposed copy): gathers straight from [C,H,W] f32.
__global__ __launch_bounds__(256) void k_sample_direct(const float* __restrict__ kpts,
                                                       const float* __restrict__ ps2,
                                                       const float* __restrict__ feats,
                                                       unsigned short* __restrict__ f12) {
    int point = blockIdx.x * 4 + (threadIdx.x >> 6);
    int lane  = threadIdx.x & 63;
    int cb    = lane * 4;

    const float* src = (point < NF1) ? (kpts + (size_t)point * 2)
                                     : (ps2 + (size_t)(point - NF1) * 2);
    float x  = src[0] - 0.5f, y = src[1] - 0.5f;
    float x0 = floorf(x), y0 = floorf(y);
    int ix0 = (int)x0, iy0 = (int)y0;
    float fx = x - x0, fy = y - y0;

    float acc[4] = {0.f, 0.f, 0.f, 0.f};
    #pragma unroll
    for (int dy = 0; dy < 2; ++dy) {
        #pragma unroll
        for (int dx = 0; dx < 2; ++dx) {
            int ix = ix0 + dx, iy = iy0 + dy;
            float w = (dx ? fx : 1.f - fx) * (dy ? fy : 1.f - fy);
            if (ix >= 0 && ix < W_ && iy >= 0 && iy < H_) {
                int base = iy * W_ + ix;
                #pragma unroll
                for (int u = 0; u < 4; ++u)
                    acc[u] += w * feats[(size_t)(cb + u) * HW_ + base];
            }
        }
    }
    ushort4 o;
    o.x = f2bf(acc[0]); o.y = f2bf(acc[1]); o.z = f2bf(acc[2]); o.w = f2bf(acc[3]);
    *(ushort4*)(f12 + (size_t)point * C_ + cb) = o;
}

// ---------------------------------------------------------------------------
// Kernel 3: bf16 MFMA sign-dot + masked distance stats.
// One wave per (o, 16-p tile, 128-n group). A-frags (full K=256) in 32 VGPRs;
// 8 n-tiles of 16, B-frags straight from global (L2-resident). mask =
// (dot >= 0). Partials layout: [o][p][g] for coalesced k_final reads.
// MFMA layouts per m89: C/D col=lane&15, row=(lane>>4)*4+reg;
// A/B m(n)=lane&15, k=(lane>>4)*8+j.
// ---------------------------------------------------------------------------
__global__ __launch_bounds__(256) void k_simdist(const unsigned short* __restrict__ f12,
                                                 const float* __restrict__ ps1,
                                                 const float* __restrict__ ps2,
                                                 float* __restrict__ pmin,
                                                 float* __restrict__ psum,
                                                 float* __restrict__ pcnt) {
    int wid  = blockIdx.x * 4 + (threadIdx.x >> 6);   // 0..2047
    int lane = threadIdx.x & 63;
    int ng = wid & 15;
    int pt = (wid >> 4) & 7;
    int o  = wid >> 7;
    int quad = lane >> 4, col = lane & 15;

    const short* f12s = (const short*)f12;
    const short8* aptr =
        (const short8*)(f12s + ((size_t)(o * NP + pt * 16 + col) * C_ + quad * 8));
    short8 a[8];
    #pragma unroll
    for (int kb = 0; kb < 8; ++kb) a[kb] = aptr[kb * 4];   // +32 bf16 per block

    const float2* ps1v = (const float2*)ps1;
    const float2* ps2v = (const float2*)ps2;
    float pxr[4], pyr[4];
    #pragma unroll
    for (int r = 0; r < 4; ++r) {
        float2 pc = ps1v[o * NP + pt * 16 + quad * 4 + r];
        pxr[r] = pc.x; pyr[r] = pc.y;
    }

    float mn[4] = {INFINITY, INFINITY, INFINITY, INFINITY};
    float sm[4] = {0.f, 0.f, 0.f, 0.f};
    float ct[4] = {0.f, 0.f, 0.f, 0.f};

    for (int t = 0; t < NT; ++t) {
        int nbase = ng * 128 + t * 16;
        const short8* bptr =
            (const short8*)(f12s + ((size_t)(NF1 + o * N2 + nbase + col) * C_ + quad * 8));
        f32x4 acc = {0.f, 0.f, 0.f, 0.f};
        #pragma unroll
        for (int kb = 0; kb < 8; ++kb)
            acc = __builtin_amdgcn_mfma_f32_16x16x32_bf16(a[kb], bptr[kb * 4], acc, 0, 0, 0);

        float2 nc = ps2v[o * N2 + nbase + col];   // this lane's n-column coords
        #pragma unroll
        for (int r = 0; r < 4; ++r) {
            if (acc[r] >= 0.f) {                  // sims >= 0  <=>  dot >= 0
                float dx = pxr[r] - nc.x, dy = pyr[r] - nc.y;
                float d  = sqrtf(dx * dx + dy * dy);
                mn[r] = fminf(mn[r], d); sm[r] += d; ct[r] += 1.f;
            }
        }
    }

    #pragma unroll
    for (int r = 0; r < 4; ++r) {
        #pragma unroll
        for (int off = 1; off < 16; off <<= 1) {
            mn[r] = fminf(mn[r], __shfl_xor(mn[r], off, 16));
            sm[r] += __shfl_xor(sm[r], off, 16);
            ct[r] += __shfl_xor(ct[r], off, 16);
        }
    }
    if (col == 0) {
        #pragma unroll
        for (int r = 0; r < 4; ++r) {
            int p   = pt * 16 + quad * 4 + r;
            int idx = (o * NP + p) * NG + ng;     // [o][p][g]
            pmin[idx] = mn[r]; psum[idx] = sm[r]; pcnt[idx] = ct[r];
        }
    }
}

// ---------------------------------------------------------------------------
// Kernel 4: combine group partials -> scalar loss. 1024 threads, contiguous
// 64 B reads per (o,p) pair.
// ---------------------------------------------------------------------------
__global__ __launch_bounds__(1024) void k_final(const float* __restrict__ pmin,
                                                const float* __restrict__ psum,
                                                const float* __restrict__ pcnt,
                                                float* __restrict__ out) {
    int t = threadIdx.x;
    float tot = 0.f;
    for (int pair = t; pair < NOBJ * NP; pair += 1024) {
        int base = pair * NG;
        const float4* pm = (const float4*)(pmin + base);
        const float4* ps = (const float4*)(psum + base);
        const float4* pc = (const float4*)(pcnt + base);
        float mn = INFINITY, sm = 0.f, ct = 0.f;
        #pragma unroll
        for (int g4 = 0; g4 < 4; ++g4) {
            float4 a = pm[g4], b = ps[g4], c = pc[g4];
            mn = fminf(mn, fminf(fminf(a.x, a.y), fminf(a.z, a.w)));
            sm += b.x + b.y + b.z + b.w;
            ct += c.x + c.y + c.z + c.w;
        }
        if (ct > 0.f) tot += 0.5f * (mn + sm / ct);
    }
    #pragma unroll
    for (int off = 32; off; off >>= 1) tot += __shfl_xor(tot, off, 64);
    __shared__ float wsum[16];
    if ((t & 63) == 0) wsum[t >> 6] = tot;
    __syncthreads();
    if (t < 64) {
        float v = (t < 16) ? wsum[t] : 0.f;
        #pragma unroll
        for (int off = 8; off; off >>= 1) v += __shfl_xor(v, off, 16);
        if (t == 0) out[0] = v * (1.0f / (NOBJ * NP));
    }
}

// ---------------------------------------------------------------------------
extern "C" void kernel_launch(void* const* d_in, const int* in_sizes, int n_in,
                              void* d_out, int out_size, void* d_ws, size_t ws_size,
                              hipStream_t stream) {
    const float* ps1   = (const float*)d_in[0];  // [16,128,2]
    const float* ps2   = (const float*)d_in[1];  // [16,2048,2]
    const float* feats = (const float*)d_in[2];  // [1,256,384,384]
    const float* kpts  = (const float*)d_in[3];  // [2048,2]
    float* out = (float*)d_out;

    const size_t sz_ftT  = (size_t)HW_ * C_ * sizeof(unsigned short);   // 75,497,472
    const size_t sz_f12  = (size_t)NPTS * C_ * sizeof(unsigned short);  // 17,825,792
    const size_t sz_part = (size_t)NOBJ * NP * NG * sizeof(float);      //    131,072

    char* ws = (char*)d_ws;
    if (ws_size >= sz_ftT + sz_f12 + 3 * sz_part) {
        unsigned short* ftT = (unsigned short*)ws;
        unsigned short* f12 = (unsigned short*)(ws + sz_ftT);
        float* pmin = (float*)(ws + sz_ftT + sz_f12);
        float* psum = (float*)(ws + sz_ftT + sz_f12 + sz_part);
        float* pcnt = (float*)(ws + sz_ftT + sz_f12 + 2 * sz_part);

        k_transpose<<<(HW_ / 64) * (C_ / 64), 256, 0, stream>>>(feats, ftT);
        k_sample<<<NPTS / 8, 256, 0, stream>>>(kpts, ps2, ftT, f12);
        k_simdist<<<NOBJ * 8 * NG / 4, 256, 0, stream>>>(f12, ps1, ps2, pmin, psum, pcnt);
        k_final<<<1, 1024, 0, stream>>>(pmin, psum, pcnt, out);
    } else {
        // Fallback: no transposed feature copy (uncoalesced gathers, but correct).
        unsigned short* f12 = (unsigned short*)ws;
        float* pmin = (float*)(ws + sz_f12);
        float* psum = (float*)(ws + sz_f12 + sz_part);
        float* pcnt = (float*)(ws + sz_f12 + 2 * sz_part);

        k_sample_direct<<<NPTS / 4, 256, 0, stream>>>(kpts, ps2, feats, f12);
        k_simdist<<<NOBJ * 8 * NG / 4, 256, 0, stream>>>(f12, ps1, ps2, pmin, psum, pcnt);
        k_final<<<1, 1024, 0, stream>>>(pmin, psum, pcnt, out);
    }
}